// Round 1
// baseline (444.815 us; speedup 1.0000x reference)
//
#include <hip/hip_runtime.h>
#include <math.h>

// MultiHeadGAT fused pipeline, fp32 baseline (round 1).
// Key restructuring: attn@h collapses to a weighted column-sum because the
// output only needs mean_i(h_prime). Softmax handled via logsumexp with the
// row-max = lrelu(c_i + max_j r_j + bias) trick (lrelu is monotone).

#define NH   4
#define TD   768
#define HID  256
#define OD   768
#define BB   16
#define LL   1024
#define RTOT (BB*LL)   // 16384 rows per head

__device__ __forceinline__ float lrelu(float x) { return fmaxf(x, 0.01f * x); }

__device__ __forceinline__ float waveReduceSum(float v) {
  #pragma unroll
  for (int m = 1; m < 64; m <<= 1) v += __shfl_xor(v, m, 64);
  return v;
}
__device__ __forceinline__ float waveReduceMax(float v) {
  #pragma unroll
  for (int m = 1; m < 64; m <<= 1) v = fmaxf(v, __shfl_xor(v, m, 64));
  return v;
}

// K1: h = LN(T @ W_fc[n] + b_fc[n]) ; sR = h.a1 ; sC = h.a2
// block: 256 thr = 4 waves. Each block: 64 rows x 256 cols.
// wave w owns rows [w*16, w*16+16); lane owns 4 consecutive cols.
__global__ __launch_bounds__(256) void k1_proj_ln(
    const float* __restrict__ T, const float* __restrict__ Wfc,
    const float* __restrict__ bfc, const float* __restrict__ lng,
    const float* __restrict__ lnb, const float* __restrict__ aw,
    float* __restrict__ h, float* __restrict__ sR, float* __restrict__ sC)
{
  const int n    = blockIdx.x >> 8;     // 256 blocks per head
  const int rc   = blockIdx.x & 255;
  const int t    = threadIdx.x;
  const int lane = t & 63;
  const int wv   = __builtin_amdgcn_readfirstlane(t >> 6);  // wave id (SGPR)
  const int c0   = lane * 4;
  const int rbase = rc * 64 + wv * 16;  // row within head

  __shared__ float Wlds[16 * HID];      // 16 k x 256 cols = 16KB

  float acc[16][4];
  #pragma unroll
  for (int r = 0; r < 16; ++r) {
    acc[r][0] = 0.f; acc[r][1] = 0.f; acc[r][2] = 0.f; acc[r][3] = 0.f;
  }

  const float* Wn = Wfc + (size_t)n * TD * HID;
  const float* A  = T + (size_t)rbase * TD;   // wave-uniform base

  for (int k0 = 0; k0 < TD; k0 += 16) {
    __syncthreads();
    // stage W chunk: 16x256 floats = 1024 float4, 4 per thread, coalesced
    const float4* Wg = (const float4*)(Wn + (size_t)k0 * HID);
    float4* Wl = (float4*)Wlds;
    #pragma unroll
    for (int i = 0; i < 4; ++i) Wl[i * 256 + t] = Wg[i * 256 + t];
    __syncthreads();

    #pragma unroll 4
    for (int k = 0; k < 16; ++k) {
      const float4 wv4 = *(const float4*)&Wlds[k * HID + c0];
      const float* ap = A + k0 + k;       // wave-uniform -> scalar/L1 path
      #pragma unroll
      for (int r = 0; r < 16; ++r) {
        const float a = ap[(size_t)r * TD];
        acc[r][0] = fmaf(a, wv4.x, acc[r][0]);
        acc[r][1] = fmaf(a, wv4.y, acc[r][1]);
        acc[r][2] = fmaf(a, wv4.z, acc[r][2]);
        acc[r][3] = fmaf(a, wv4.w, acc[r][3]);
      }
    }
  }

  const float4 bf = *(const float4*)(bfc + n * HID + c0);
  const float4 gv = *(const float4*)(lng + n * HID + c0);
  const float4 bv = *(const float4*)(lnb + n * HID + c0);
  const float4 a1 = *(const float4*)(aw + n * (2 * HID) + c0);
  const float4 a2 = *(const float4*)(aw + n * (2 * HID) + HID + c0);

  float* hbase = h + ((size_t)n * RTOT + rbase) * HID;

  #pragma unroll
  for (int r = 0; r < 16; ++r) {
    const float x0 = acc[r][0] + bf.x, x1 = acc[r][1] + bf.y;
    const float x2 = acc[r][2] + bf.z, x3 = acc[r][3] + bf.w;
    float s  = x0 + x1 + x2 + x3;
    float s2 = x0*x0 + x1*x1 + x2*x2 + x3*x3;
    s  = waveReduceSum(s);
    s2 = waveReduceSum(s2);
    const float mu  = s * (1.f / HID);
    const float var = s2 * (1.f / HID) - mu * mu;
    const float rs  = rsqrtf(var + 1e-5f);
    float4 hn;
    hn.x = (x0 - mu) * rs * gv.x + bv.x;
    hn.y = (x1 - mu) * rs * gv.y + bv.y;
    hn.z = (x2 - mu) * rs * gv.z + bv.z;
    hn.w = (x3 - mu) * rs * gv.w + bv.w;
    float pr = hn.x*a1.x + hn.y*a1.y + hn.z*a1.z + hn.w*a1.w;
    float pc = hn.x*a2.x + hn.y*a2.y + hn.z*a2.z + hn.w*a2.w;
    pr = waveReduceSum(pr);
    pc = waveReduceSum(pc);
    *(float4*)(hbase + (size_t)r * HID + c0) = hn;
    if (lane == 0) {
      sR[n * RTOT + rbase + r] = pr;
      sC[n * RTOT + rbase + r] = pc;
    }
  }
}

// K2a: q[n,b,i] = m_i + log(sum_j exp(lrelu(c_i + r_j + ab) - m_i)),
//      m_i = lrelu(c_i + rmax + ab)  (valid: lrelu monotone)
__global__ __launch_bounds__(256) void k2_logsumexp(
    const float* __restrict__ sR, const float* __restrict__ sC,
    const float* __restrict__ ab, float* __restrict__ q)
{
  const int n  = blockIdx.x >> 6;
  const int b  = (blockIdx.x >> 2) & 15;
  const int ic = blockIdx.x & 3;
  const int t  = threadIdx.x;
  const int base = (n * BB + b) * LL;

  __shared__ float rl[LL];
  __shared__ float red[4];

  const float4 r4 = ((const float4*)(sR + base))[t];
  ((float4*)rl)[t] = r4;
  float tm = fmaxf(fmaxf(r4.x, r4.y), fmaxf(r4.z, r4.w));
  tm = waveReduceMax(tm);
  if ((t & 63) == 0) red[t >> 6] = tm;
  __syncthreads();
  const float rmax = fmaxf(fmaxf(red[0], red[1]), fmaxf(red[2], red[3]));

  const int i = ic * 256 + t;
  const float ci = sC[base + i] + ab[n];
  const float m = lrelu(ci + rmax);
  float z = 0.f;
  #pragma unroll 4
  for (int j4 = 0; j4 < LL / 4; ++j4) {
    const float4 rr = ((const float4*)rl)[j4];
    z += __expf(lrelu(ci + rr.x) - m);
    z += __expf(lrelu(ci + rr.y) - m);
    z += __expf(lrelu(ci + rr.z) - m);
    z += __expf(lrelu(ci + rr.w) - m);
  }
  q[base + i] = m + __logf(z);
}

// K2b: wcol[n,b,j] = (1/L) * sum_i exp(lrelu(c_i + r_j + ab) - q_i)
__global__ __launch_bounds__(256) void k2_colsum(
    const float* __restrict__ sR, const float* __restrict__ sC,
    const float* __restrict__ ab, const float* __restrict__ q,
    float* __restrict__ wcol)
{
  const int n  = blockIdx.x >> 6;
  const int b  = (blockIdx.x >> 2) & 15;
  const int jc = blockIdx.x & 3;
  const int t  = threadIdx.x;
  const int base = (n * BB + b) * LL;

  __shared__ float cl[LL];
  __shared__ float ql[LL];
  ((float4*)cl)[t] = ((const float4*)(sC + base))[t];
  ((float4*)ql)[t] = ((const float4*)(q + base))[t];
  __syncthreads();

  const int j = jc * 256 + t;
  const float rj = sR[base + j] + ab[n];
  float acc = 0.f;
  #pragma unroll 4
  for (int i4 = 0; i4 < LL / 4; ++i4) {
    const float4 cc = ((const float4*)cl)[i4];
    const float4 qq = ((const float4*)ql)[i4];
    acc += __expf(lrelu(cc.x + rj) - qq.x);
    acc += __expf(lrelu(cc.y + rj) - qq.y);
    acc += __expf(lrelu(cc.z + rj) - qq.z);
    acc += __expf(lrelu(cc.w + rj) - qq.w);
  }
  wcol[base + j] = acc * (1.f / LL);
}

// K3a: partial[n,b,jc,c] = sum_{j in chunk} wcol[j] * h[n,b,j,c]
__global__ __launch_bounds__(256) void k3_wsum(
    const float* __restrict__ h, const float* __restrict__ wcol,
    float* __restrict__ partial)
{
  const int n  = blockIdx.x >> 6;
  const int b  = (blockIdx.x >> 2) & 15;
  const int jc = blockIdx.x & 3;
  const int t  = threadIdx.x;
  __shared__ float wl[256];
  const int base = (n * BB + b) * LL;
  wl[t] = wcol[base + jc * 256 + t];
  __syncthreads();
  const float* hp = h + ((size_t)n * RTOT + b * LL + jc * 256) * HID + t;
  float acc = 0.f;
  #pragma unroll 8
  for (int j = 0; j < 256; ++j) acc = fmaf(wl[j], hp[(size_t)j * HID], acc);
  partial[((n * BB + b) * 4 + jc) * 256 + t] = acc;
}

// K3b: sent_raw[b, n*HID + c] = sum_jc partial
__global__ __launch_bounds__(256) void k3_reduce(
    const float* __restrict__ partial, float* __restrict__ sent_raw)
{
  const int n = blockIdx.x >> 4;
  const int b = blockIdx.x & 15;
  const int t = threadIdx.x;
  const int pb = (n * BB + b) * 4 * 256;
  const float v = partial[pb + t] + partial[pb + 256 + t] +
                  partial[pb + 512 + t] + partial[pb + 768 + t];
  sent_raw[b * (NH * HID) + n * HID + t] = v;
}

// K4a: cat_pre[b,o] = sent_raw[b,:] @ W_cat[:,o] + b_cat[o]
__global__ __launch_bounds__(256) void k4_cat(
    const float* __restrict__ sent_raw, const float* __restrict__ Wcat,
    const float* __restrict__ bcat, float* __restrict__ cat_pre)
{
  const int b  = blockIdx.x / 3;
  const int oc = blockIdx.x % 3;
  const int t  = threadIdx.x;
  const int o  = oc * 256 + t;
  __shared__ float s[NH * HID];   // 1024
  ((float4*)s)[t] = ((const float4*)(sent_raw + b * (NH * HID)))[t];
  __syncthreads();
  float acc = 0.f;
  #pragma unroll 4
  for (int k4 = 0; k4 < (NH * HID) / 4; ++k4) {
    const float4 sv = ((const float4*)s)[k4];
    const float* wp = Wcat + (size_t)(k4 * 4) * OD + o;
    acc = fmaf(sv.x, wp[0],      acc);
    acc = fmaf(sv.y, wp[OD],     acc);
    acc = fmaf(sv.z, wp[2 * OD], acc);
    acc = fmaf(sv.w, wp[3 * OD], acc);
  }
  cat_pre[b * OD + o] = acc + bcat[o];
}

// K4b: sent = LN(cat_pre); write to ws + d_out (4th output slot)
__global__ __launch_bounds__(256) void k4_ln(
    const float* __restrict__ cat_pre, const float* __restrict__ g,
    const float* __restrict__ be, float* __restrict__ sent,
    float* __restrict__ out_sent)
{
  const int b = blockIdx.x;
  const int t = threadIdx.x;
  __shared__ float red[4][2];
  const float x0 = cat_pre[b * OD + t];
  const float x1 = cat_pre[b * OD + 256 + t];
  const float x2 = cat_pre[b * OD + 512 + t];
  float s  = x0 + x1 + x2;
  float s2 = x0*x0 + x1*x1 + x2*x2;
  s = waveReduceSum(s); s2 = waveReduceSum(s2);
  if ((t & 63) == 0) { red[t >> 6][0] = s; red[t >> 6][1] = s2; }
  __syncthreads();
  s  = red[0][0] + red[1][0] + red[2][0] + red[3][0];
  s2 = red[0][1] + red[1][1] + red[2][1] + red[3][1];
  const float mu  = s * (1.f / OD);
  const float var = s2 * (1.f / OD) - mu * mu;
  const float rs  = rsqrtf(var + 1e-5f);
  #pragma unroll
  for (int i = 0; i < 3; ++i) {
    const int o = i * 256 + t;
    const float x = (i == 0 ? x0 : (i == 1 ? x1 : x2));
    const float y = (x - mu) * rs * g[o] + be[o];
    sent[b * OD + o]     = y;
    out_sent[b * OD + o] = y;
  }
}

// K4c: dims_out[i][b,o] = sent[b,:] @ W_fcs[i][:,o] + b_fcs[i,o]
__global__ __launch_bounds__(256) void k4_fcs(
    const float* __restrict__ sent, const float* __restrict__ Wfcs,
    const float* __restrict__ bfcs, float* __restrict__ out)
{
  const int i = blockIdx.x >> 4;
  const int b = blockIdx.x & 15;
  const int t = threadIdx.x;
  __shared__ float s[OD];
  s[t]       = sent[b * OD + t];
  s[t + 256] = sent[b * OD + 256 + t];
  s[t + 512] = sent[b * OD + 512 + t];
  __syncthreads();
  float a0 = 0.f, a1 = 0.f, a2 = 0.f;
  const float* W = Wfcs + (size_t)i * OD * OD;
  #pragma unroll 2
  for (int k4 = 0; k4 < OD / 4; ++k4) {
    const float4 sv = ((const float4*)s)[k4];
    const float* wp = W + (size_t)(k4 * 4) * OD + t;
    a0 = fmaf(sv.x, wp[0],            a0);
    a1 = fmaf(sv.x, wp[256],          a1);
    a2 = fmaf(sv.x, wp[512],          a2);
    a0 = fmaf(sv.y, wp[OD],           a0);
    a1 = fmaf(sv.y, wp[OD + 256],     a1);
    a2 = fmaf(sv.y, wp[OD + 512],     a2);
    a0 = fmaf(sv.z, wp[2 * OD],       a0);
    a1 = fmaf(sv.z, wp[2 * OD + 256], a1);
    a2 = fmaf(sv.z, wp[2 * OD + 512], a2);
    a0 = fmaf(sv.w, wp[3 * OD],       a0);
    a1 = fmaf(sv.w, wp[3 * OD + 256], a1);
    a2 = fmaf(sv.w, wp[3 * OD + 512], a2);
  }
  out[i * (BB * OD) + b * OD + t]       = a0 + bfcs[i * OD + t];
  out[i * (BB * OD) + b * OD + 256 + t] = a1 + bfcs[i * OD + 256 + t];
  out[i * (BB * OD) + b * OD + 512 + t] = a2 + bfcs[i * OD + 512 + t];
}

extern "C" void kernel_launch(void* const* d_in, const int* in_sizes, int n_in,
                              void* d_out, int out_size, void* d_ws, size_t ws_size,
                              hipStream_t stream)
{
  const float* T    = (const float*)d_in[0];
  const float* Wfc  = (const float*)d_in[1];
  const float* bfc  = (const float*)d_in[2];
  const float* lng  = (const float*)d_in[3];
  const float* lnb  = (const float*)d_in[4];
  const float* aw   = (const float*)d_in[5];
  const float* ab   = (const float*)d_in[6];
  const float* Wcat = (const float*)d_in[7];
  const float* bcat = (const float*)d_in[8];
  const float* lnOg = (const float*)d_in[9];
  const float* lnOb = (const float*)d_in[10];
  const float* Wfcs = (const float*)d_in[11];
  const float* bfcs = (const float*)d_in[12];
  float* out = (float*)d_out;

  float* ws       = (float*)d_ws;
  float* h        = ws;                               // 4*16384*256 = 16,777,216
  float* sR       = h + (size_t)NH * RTOT * HID;      // 65536
  float* sC       = sR + NH * RTOT;                   // 65536
  float* q        = sC + NH * RTOT;                   // 65536
  float* wcol     = q + NH * RTOT;                    // 65536
  float* partial  = wcol + NH * RTOT;                 // 65536
  float* sent_raw = partial + NH * BB * 4 * 256;      // 16384
  float* cat_pre  = sent_raw + BB * NH * HID;         // 12288
  float* sent     = cat_pre + BB * OD;                // 12288

  k1_proj_ln  <<<dim3(NH * 256), dim3(256), 0, stream>>>(T, Wfc, bfc, lng, lnb, aw, h, sR, sC);
  k2_logsumexp<<<dim3(256),      dim3(256), 0, stream>>>(sR, sC, ab, q);
  k2_colsum   <<<dim3(256),      dim3(256), 0, stream>>>(sR, sC, ab, q, wcol);
  k3_wsum     <<<dim3(256),      dim3(256), 0, stream>>>(h, wcol, partial);
  k3_reduce   <<<dim3(64),       dim3(256), 0, stream>>>(partial, sent_raw);
  k4_cat      <<<dim3(48),       dim3(256), 0, stream>>>(sent_raw, Wcat, bcat, cat_pre);
  k4_ln       <<<dim3(16),       dim3(256), 0, stream>>>(cat_pre, lnOg, lnOb, sent, out + 3 * BB * OD);
  k4_fcs      <<<dim3(48),       dim3(256), 0, stream>>>(sent, Wfcs, bfcs, out);
}

// Round 2
// 203.953 us; speedup vs baseline: 2.1810x; 2.1810x over previous
//
#include <hip/hip_runtime.h>
#include <math.h>

// MultiHeadGAT fused pipeline, round 2: K1 -> bf16 MFMA GEMM.
// attn@h collapses to weighted column-sum (output only needs mean_i h_prime);
// softmax via logsumexp with row-max = lrelu(c_i + max_j r_j + b) (monotone).

#define NH   4
#define TD   768
#define HID  256
#define OD   768
#define BB   16
#define LL   1024
#define RTOT (BB*LL)   // 16384 rows per head

typedef __attribute__((ext_vector_type(8))) short bf16x8;
typedef __attribute__((ext_vector_type(4))) float f32x4;

__device__ __forceinline__ float lrelu(float x) { return fmaxf(x, 0.01f * x); }

__device__ __forceinline__ float waveReduceSum(float v) {
  #pragma unroll
  for (int m = 1; m < 64; m <<= 1) v += __shfl_xor(v, m, 64);
  return v;
}
__device__ __forceinline__ float waveReduceMax(float v) {
  #pragma unroll
  for (int m = 1; m < 64; m <<= 1) v = fmaxf(v, __shfl_xor(v, m, 64));
  return v;
}
__device__ __forceinline__ float red16(float v) {   // reduce across 16-lane group
  v += __shfl_xor(v, 1, 64); v += __shfl_xor(v, 2, 64);
  v += __shfl_xor(v, 4, 64); v += __shfl_xor(v, 8, 64);
  return v;
}

__device__ __forceinline__ unsigned short f2b(float f) {  // f32 -> bf16 RNE
  union { float f; unsigned u; } v; v.f = f;
  unsigned u = v.u;
  return (unsigned short)((u + 0x7fffu + ((u >> 16) & 1u)) >> 16);
}
__device__ __forceinline__ float b2f(unsigned short h) {
  union { unsigned u; float f; } v; v.u = ((unsigned)h) << 16;
  return v.f;
}

// async 16B global->LDS (addrspacecast, NOT inttoptr, so LDS aperture is handled)
__device__ __forceinline__ void gll16(const void* g, void* l) {
  __builtin_amdgcn_global_load_lds(
      (const __attribute__((address_space(1))) unsigned int*)g,
      (__attribute__((address_space(3))) unsigned int*)l, 16, 0, 0);
}

// ---- conversion kernels ----------------------------------------------------
// T fp32 [16384][768] -> bf16 (row-major unchanged)
__global__ __launch_bounds__(256) void kconv_t(const float* __restrict__ src,
                                               unsigned short* __restrict__ dst) {
  const size_t i = ((size_t)blockIdx.x * 256 + threadIdx.x) * 8;
  const float4 a = *(const float4*)(src + i);
  const float4 b = *(const float4*)(src + i + 4);
  bf16x8 o;
  o[0] = (short)f2b(a.x); o[1] = (short)f2b(a.y);
  o[2] = (short)f2b(a.z); o[3] = (short)f2b(a.w);
  o[4] = (short)f2b(b.x); o[5] = (short)f2b(b.y);
  o[6] = (short)f2b(b.z); o[7] = (short)f2b(b.w);
  *(bf16x8*)(dst + i) = o;
}

// Wfc fp32 [n][k=768][c=256] -> bf16 transposed Wt [n][c=256][k=768]
__global__ __launch_bounds__(256) void kconv_w(const float* __restrict__ src,
                                               unsigned short* __restrict__ dst) {
  const int ct = blockIdx.x, kt = blockIdx.y, n = blockIdx.z;
  const int t = threadIdx.x;
  __shared__ float tile[64][65];
  #pragma unroll
  for (int i = 0; i < 16; ++i) {
    const int kl = i * 4 + (t >> 6), cl = t & 63;
    tile[kl][cl] = src[(size_t)n * TD * HID + (size_t)(kt * 64 + kl) * HID + ct * 64 + cl];
  }
  __syncthreads();
  #pragma unroll
  for (int i = 0; i < 16; ++i) {
    const int cl = i * 4 + (t >> 6), kl = t & 63;
    dst[(size_t)n * HID * TD + (size_t)(ct * 64 + cl) * TD + kt * 64 + kl] =
        f2b(tile[kl][cl]);
  }
}

// ---- K1: MFMA GEMM + fused LN + a1/a2 dots ---------------------------------
// block = 64 rows x 256 cols of head n; 4 waves, wave wq owns cols [64wq,64wq+64)
// LDS: As[64][64] bf16 (8KB) + Bs[256][64] bf16 (32KB) = 40960B -> 4 blk/CU (LDS)
__global__ __launch_bounds__(256) void k1_mfma(
    const unsigned short* __restrict__ Tb,   // [16384][768] bf16
    const unsigned short* __restrict__ Wtb,  // [4][256][768] bf16 (W^T)
    const float* __restrict__ bfc, const float* __restrict__ lng,
    const float* __restrict__ lnb, const float* __restrict__ aw,
    unsigned short* __restrict__ hb,         // [4][16384][256] bf16
    float* __restrict__ sR, float* __restrict__ sC)
{
  const int n    = blockIdx.x >> 8;
  const int mb   = blockIdx.x & 255;
  const int t    = threadIdx.x;
  const int lane = t & 63;
  const int wq   = __builtin_amdgcn_readfirstlane(t >> 6);
  const int cl   = lane & 15;
  const int rg   = lane >> 4;
  const int row0 = mb * 64;

  __shared__ __align__(16) char smem[40960];
  unsigned short* As = (unsigned short*)smem;            // [64][64]
  unsigned short* Bs = (unsigned short*)(smem + 8192);   // [256][64]

  f32x4 acc[4][4];
  #pragma unroll
  for (int mi = 0; mi < 4; ++mi)
    #pragma unroll
    for (int ni = 0; ni < 4; ++ni) acc[mi][ni] = (f32x4){0.f, 0.f, 0.f, 0.f};

  const char* Tg = (const char*)Tb;
  const char* Wg = (const char*)(Wtb + (size_t)n * HID * TD);

  for (int k0 = 0; k0 < TD; k0 += 64) {
    if (k0) __syncthreads();
    // stage A: 8KB (2 x 4KB chunks), 128B per row (64 bf16)
    #pragma unroll
    for (int i = 0; i < 2; ++i) {
      const int off = i * 4096 + t * 16;
      const int r = off >> 7, kb = off & 127;
      gll16(Tg + ((size_t)(row0 + r) * TD + k0) * 2 + kb, smem + off);
    }
    // stage B^T: 32KB (8 x 4KB chunks)
    #pragma unroll
    for (int i = 0; i < 8; ++i) {
      const int off = i * 4096 + t * 16;
      const int c = off >> 7, kb = off & 127;
      gll16(Wg + ((size_t)c * TD + k0) * 2 + kb, smem + 8192 + off);
    }
    __syncthreads();   // drains vmcnt (global_load_lds) + publishes tiles

    #pragma unroll
    for (int ks = 0; ks < 64; ks += 32) {
      bf16x8 av[4], bv[4];
      const int kk = ks + rg * 8;
      #pragma unroll
      for (int mi = 0; mi < 4; ++mi)
        av[mi] = *(const bf16x8*)&As[(mi * 16 + cl) * 64 + kk];
      #pragma unroll
      for (int ni = 0; ni < 4; ++ni)
        bv[ni] = *(const bf16x8*)&Bs[(wq * 64 + ni * 16 + cl) * 64 + kk];
      #pragma unroll
      for (int mi = 0; mi < 4; ++mi)
        #pragma unroll
        for (int ni = 0; ni < 4; ++ni)
          acc[mi][ni] = __builtin_amdgcn_mfma_f32_16x16x32_bf16(
              av[mi], bv[ni], acc[mi][ni], 0, 0, 0);
    }
  }

  // ---- epilogue: bias, LN stats (cross-wave), h, a1/a2 dots, bf16 store ----
  float* redS  = (float*)smem;              // [64][4]
  float* redS2 = (float*)(smem + 1024);
  float* redP  = (float*)(smem + 2048);
  float* redC  = (float*)(smem + 3072);
  unsigned short* hs = (unsigned short*)(smem + 4096);   // [64][264] padded

  float bfn[4], gvn[4], bvn[4], a1n[4], a2n[4];
  #pragma unroll
  for (int ni = 0; ni < 4; ++ni) {
    const int c = wq * 64 + ni * 16 + cl;
    bfn[ni] = bfc[n * HID + c];
    gvn[ni] = lng[n * HID + c];
    bvn[ni] = lnb[n * HID + c];
    a1n[ni] = aw[n * (2 * HID) + c];
    a2n[ni] = aw[n * (2 * HID) + HID + c];
  }
  #pragma unroll
  for (int mi = 0; mi < 4; ++mi)
    #pragma unroll
    for (int ni = 0; ni < 4; ++ni) acc[mi][ni] += bfn[ni];

  __syncthreads();   // all frag reads done; As/Bs regions now reusable
  #pragma unroll
  for (int mi = 0; mi < 4; ++mi) {
    #pragma unroll
    for (int r = 0; r < 4; ++r) {
      const float x0 = acc[mi][0][r], x1 = acc[mi][1][r];
      const float x2 = acc[mi][2][r], x3 = acc[mi][3][r];
      const float s  = red16(x0 + x1 + x2 + x3);
      const float s2 = red16(x0*x0 + x1*x1 + x2*x2 + x3*x3);
      if (cl == 0) {
        const int row = mi * 16 + rg * 4 + r;
        redS[row * 4 + wq] = s; redS2[row * 4 + wq] = s2;
      }
    }
  }
  __syncthreads();
  #pragma unroll
  for (int mi = 0; mi < 4; ++mi) {
    #pragma unroll
    for (int r = 0; r < 4; ++r) {
      const int row = mi * 16 + rg * 4 + r;
      const f32x4 sv  = *(const f32x4*)&redS[row * 4];
      const f32x4 s2v = *(const f32x4*)&redS2[row * 4];
      const float st  = sv.x + sv.y + sv.z + sv.w;
      const float s2t = s2v.x + s2v.y + s2v.z + s2v.w;
      const float mu  = st * (1.f / HID);
      const float var = s2t * (1.f / HID) - mu * mu;
      const float rs  = rsqrtf(var + 1e-5f);
      float pr = 0.f, pc = 0.f;
      #pragma unroll
      for (int ni = 0; ni < 4; ++ni) {
        const float hv = (acc[mi][ni][r] - mu) * rs * gvn[ni] + bvn[ni];
        hs[row * 264 + wq * 64 + ni * 16 + cl] = f2b(hv);
        pr += hv * a1n[ni]; pc += hv * a2n[ni];
      }
      pr = red16(pr); pc = red16(pc);
      if (cl == 0) { redP[row * 4 + wq] = pr; redC[row * 4 + wq] = pc; }
    }
  }
  __syncthreads();
  if (t < 64) {
    const f32x4 pv = *(const f32x4*)&redP[t * 4];
    const f32x4 cv = *(const f32x4*)&redC[t * 4];
    sR[n * RTOT + row0 + t] = pv.x + pv.y + pv.z + pv.w;
    sC[n * RTOT + row0 + t] = cv.x + cv.y + cv.z + cv.w;
  }
  unsigned short* hgb = hb + ((size_t)n * RTOT + row0) * HID;
  #pragma unroll
  for (int i = 0; i < 8; ++i) {
    const int e = i * 2048 + t * 8;
    const int row = e >> 8, c = e & 255;
    const bf16x8 v = *(const bf16x8*)&hs[row * 264 + c];
    *(bf16x8*)&hgb[(size_t)row * HID + c] = v;
  }
}

// K2a: q[n,b,i] = m_i + log(sum_j exp(lrelu(c_i + r_j + ab) - m_i))
__global__ __launch_bounds__(256) void k2_logsumexp(
    const float* __restrict__ sR, const float* __restrict__ sC,
    const float* __restrict__ ab, float* __restrict__ q)
{
  const int n  = blockIdx.x >> 6;
  const int b  = (blockIdx.x >> 2) & 15;
  const int ic = blockIdx.x & 3;
  const int t  = threadIdx.x;
  const int base = (n * BB + b) * LL;

  __shared__ float rl[LL];
  __shared__ float red[4];

  const float4 r4 = ((const float4*)(sR + base))[t];
  ((float4*)rl)[t] = r4;
  float tm = fmaxf(fmaxf(r4.x, r4.y), fmaxf(r4.z, r4.w));
  tm = waveReduceMax(tm);
  if ((t & 63) == 0) red[t >> 6] = tm;
  __syncthreads();
  const float rmax = fmaxf(fmaxf(red[0], red[1]), fmaxf(red[2], red[3]));

  const int i = ic * 256 + t;
  const float ci = sC[base + i] + ab[n];
  const float m = lrelu(ci + rmax);
  float z = 0.f;
  #pragma unroll 4
  for (int j4 = 0; j4 < LL / 4; ++j4) {
    const float4 rr = ((const float4*)rl)[j4];
    z += __expf(lrelu(ci + rr.x) - m);
    z += __expf(lrelu(ci + rr.y) - m);
    z += __expf(lrelu(ci + rr.z) - m);
    z += __expf(lrelu(ci + rr.w) - m);
  }
  q[base + i] = m + __logf(z);
}

// K2b: wcol[n,b,j] = (1/L) * sum_i exp(lrelu(c_i + r_j + ab) - q_i)
__global__ __launch_bounds__(256) void k2_colsum(
    const float* __restrict__ sR, const float* __restrict__ sC,
    const float* __restrict__ ab, const float* __restrict__ q,
    float* __restrict__ wcol)
{
  const int n  = blockIdx.x >> 6;
  const int b  = (blockIdx.x >> 2) & 15;
  const int jc = blockIdx.x & 3;
  const int t  = threadIdx.x;
  const int base = (n * BB + b) * LL;

  __shared__ float cl[LL];
  __shared__ float ql[LL];
  ((float4*)cl)[t] = ((const float4*)(sC + base))[t];
  ((float4*)ql)[t] = ((const float4*)(q + base))[t];
  __syncthreads();

  const int j = jc * 256 + t;
  const float rj = sR[base + j] + ab[n];
  float acc = 0.f;
  #pragma unroll 4
  for (int i4 = 0; i4 < LL / 4; ++i4) {
    const float4 cc = ((const float4*)cl)[i4];
    const float4 qq = ((const float4*)ql)[i4];
    acc += __expf(lrelu(cc.x + rj) - qq.x);
    acc += __expf(lrelu(cc.y + rj) - qq.y);
    acc += __expf(lrelu(cc.z + rj) - qq.z);
    acc += __expf(lrelu(cc.w + rj) - qq.w);
  }
  wcol[base + j] = acc * (1.f / LL);
}

// K3a: partial[n,b,jc,c] = sum_{j in chunk} wcol[j] * h[n,b,j,c]  (h is bf16)
__global__ __launch_bounds__(256) void k3_wsum(
    const unsigned short* __restrict__ h, const float* __restrict__ wcol,
    float* __restrict__ partial)
{
  const int n  = blockIdx.x >> 6;
  const int b  = (blockIdx.x >> 2) & 15;
  const int jc = blockIdx.x & 3;
  const int t  = threadIdx.x;
  __shared__ float wl[256];
  const int base = (n * BB + b) * LL;
  wl[t] = wcol[base + jc * 256 + t];
  __syncthreads();
  const unsigned short* hp =
      h + ((size_t)n * RTOT + b * LL + jc * 256) * HID + t;
  float acc = 0.f;
  #pragma unroll 8
  for (int j = 0; j < 256; ++j) acc = fmaf(wl[j], b2f(hp[(size_t)j * HID]), acc);
  partial[((n * BB + b) * 4 + jc) * 256 + t] = acc;
}

// K3b: sent_raw[b, n*HID + c] = sum_jc partial
__global__ __launch_bounds__(256) void k3_reduce(
    const float* __restrict__ partial, float* __restrict__ sent_raw)
{
  const int n = blockIdx.x >> 4;
  const int b = blockIdx.x & 15;
  const int t = threadIdx.x;
  const int pb = (n * BB + b) * 4 * 256;
  const float v = partial[pb + t] + partial[pb + 256 + t] +
                  partial[pb + 512 + t] + partial[pb + 768 + t];
  sent_raw[b * (NH * HID) + n * HID + t] = v;
}

// K4a: cat_pre[b,o] = sent_raw[b,:] @ W_cat[:,o] + b_cat[o]
__global__ __launch_bounds__(256) void k4_cat(
    const float* __restrict__ sent_raw, const float* __restrict__ Wcat,
    const float* __restrict__ bcat, float* __restrict__ cat_pre)
{
  const int b  = blockIdx.x / 3;
  const int oc = blockIdx.x % 3;
  const int t  = threadIdx.x;
  const int o  = oc * 256 + t;
  __shared__ float s[NH * HID];
  ((float4*)s)[t] = ((const float4*)(sent_raw + b * (NH * HID)))[t];
  __syncthreads();
  float acc = 0.f;
  #pragma unroll 4
  for (int k4 = 0; k4 < (NH * HID) / 4; ++k4) {
    const float4 sv = ((const float4*)s)[k4];
    const float* wp = Wcat + (size_t)(k4 * 4) * OD + o;
    acc = fmaf(sv.x, wp[0],      acc);
    acc = fmaf(sv.y, wp[OD],     acc);
    acc = fmaf(sv.z, wp[2 * OD], acc);
    acc = fmaf(sv.w, wp[3 * OD], acc);
  }
  cat_pre[b * OD + o] = acc + bcat[o];
}

// K4b: sent = LN(cat_pre)
__global__ __launch_bounds__(256) void k4_ln(
    const float* __restrict__ cat_pre, const float* __restrict__ g,
    const float* __restrict__ be, float* __restrict__ sent,
    float* __restrict__ out_sent)
{
  const int b = blockIdx.x;
  const int t = threadIdx.x;
  __shared__ float red[4][2];
  const float x0 = cat_pre[b * OD + t];
  const float x1 = cat_pre[b * OD + 256 + t];
  const float x2 = cat_pre[b * OD + 512 + t];
  float s  = x0 + x1 + x2;
  float s2 = x0*x0 + x1*x1 + x2*x2;
  s = waveReduceSum(s); s2 = waveReduceSum(s2);
  if ((t & 63) == 0) { red[t >> 6][0] = s; red[t >> 6][1] = s2; }
  __syncthreads();
  s  = red[0][0] + red[1][0] + red[2][0] + red[3][0];
  s2 = red[0][1] + red[1][1] + red[2][1] + red[3][1];
  const float mu  = s * (1.f / OD);
  const float var = s2 * (1.f / OD) - mu * mu;
  const float rs  = rsqrtf(var + 1e-5f);
  #pragma unroll
  for (int i = 0; i < 3; ++i) {
    const int o = i * 256 + t;
    const float x = (i == 0 ? x0 : (i == 1 ? x1 : x2));
    const float y = (x - mu) * rs * g[o] + be[o];
    sent[b * OD + o]     = y;
    out_sent[b * OD + o] = y;
  }
}

// K4c: dims_out[i][b,o] = sent[b,:] @ W_fcs[i][:,o] + b_fcs[i,o]
__global__ __launch_bounds__(256) void k4_fcs(
    const float* __restrict__ sent, const float* __restrict__ Wfcs,
    const float* __restrict__ bfcs, float* __restrict__ out)
{
  const int i = blockIdx.x >> 4;
  const int b = blockIdx.x & 15;
  const int t = threadIdx.x;
  __shared__ float s[OD];
  s[t]       = sent[b * OD + t];
  s[t + 256] = sent[b * OD + 256 + t];
  s[t + 512] = sent[b * OD + 512 + t];
  __syncthreads();
  float a0 = 0.f, a1 = 0.f, a2 = 0.f;
  const float* W = Wfcs + (size_t)i * OD * OD;
  #pragma unroll 2
  for (int k4 = 0; k4 < OD / 4; ++k4) {
    const float4 sv = ((const float4*)s)[k4];
    const float* wp = W + (size_t)(k4 * 4) * OD + t;
    a0 = fmaf(sv.x, wp[0],            a0);
    a1 = fmaf(sv.x, wp[256],          a1);
    a2 = fmaf(sv.x, wp[512],          a2);
    a0 = fmaf(sv.y, wp[OD],           a0);
    a1 = fmaf(sv.y, wp[OD + 256],     a1);
    a2 = fmaf(sv.y, wp[OD + 512],     a2);
    a0 = fmaf(sv.z, wp[2 * OD],       a0);
    a1 = fmaf(sv.z, wp[2 * OD + 256], a1);
    a2 = fmaf(sv.z, wp[2 * OD + 512], a2);
    a0 = fmaf(sv.w, wp[3 * OD],       a0);
    a1 = fmaf(sv.w, wp[3 * OD + 256], a1);
    a2 = fmaf(sv.w, wp[3 * OD + 512], a2);
  }
  out[i * (BB * OD) + b * OD + t]       = a0 + bfcs[i * OD + t];
  out[i * (BB * OD) + b * OD + 256 + t] = a1 + bfcs[i * OD + 256 + t];
  out[i * (BB * OD) + b * OD + 512 + t] = a2 + bfcs[i * OD + 512 + t];
}

extern "C" void kernel_launch(void* const* d_in, const int* in_sizes, int n_in,
                              void* d_out, int out_size, void* d_ws, size_t ws_size,
                              hipStream_t stream)
{
  const float* T    = (const float*)d_in[0];
  const float* Wfc  = (const float*)d_in[1];
  const float* bfc  = (const float*)d_in[2];
  const float* lng  = (const float*)d_in[3];
  const float* lnb  = (const float*)d_in[4];
  const float* aw   = (const float*)d_in[5];
  const float* ab   = (const float*)d_in[6];
  const float* Wcat = (const float*)d_in[7];
  const float* bcat = (const float*)d_in[8];
  const float* lnOg = (const float*)d_in[9];
  const float* lnOb = (const float*)d_in[10];
  const float* Wfcs = (const float*)d_in[11];
  const float* bfcs = (const float*)d_in[12];
  float* out = (float*)d_out;

  char* W = (char*)d_ws;
  unsigned short* Tb  = (unsigned short*)W;                 // 16384*768
  unsigned short* Wtb = (unsigned short*)(W + 25165824);    // 4*256*768
  unsigned short* hb  = (unsigned short*)(W + 26738688);    // 4*16384*256
  float* sR       = (float*)(W + 60293120);
  float* sC       = sR + NH * RTOT;
  float* q        = sC + NH * RTOT;
  float* wcol     = q + NH * RTOT;
  float* partial  = wcol + NH * RTOT;
  float* sent_raw = partial + NH * BB * 4 * 256;
  float* cat_pre  = sent_raw + BB * NH * HID;
  float* sent     = cat_pre + BB * OD;

  kconv_t     <<<dim3(6144),     dim3(256), 0, stream>>>(T, Tb);
  kconv_w     <<<dim3(4, 12, 4), dim3(256), 0, stream>>>(Wfc, Wtb);
  k1_mfma     <<<dim3(NH * 256), dim3(256), 0, stream>>>(Tb, Wtb, bfc, lng, lnb, aw, hb, sR, sC);
  k2_logsumexp<<<dim3(256),      dim3(256), 0, stream>>>(sR, sC, ab, q);
  k2_colsum   <<<dim3(256),      dim3(256), 0, stream>>>(sR, sC, ab, q, wcol);
  k3_wsum     <<<dim3(256),      dim3(256), 0, stream>>>(hb, wcol, partial);
  k3_reduce   <<<dim3(64),       dim3(256), 0, stream>>>(partial, sent_raw);
  k4_cat      <<<dim3(48),       dim3(256), 0, stream>>>(sent_raw, Wcat, bcat, cat_pre);
  k4_ln       <<<dim3(16),       dim3(256), 0, stream>>>(cat_pre, lnOg, lnOb, sent, out + 3 * BB * OD);
  k4_fcs      <<<dim3(48),       dim3(256), 0, stream>>>(sent, Wfcs, bfcs, out);
}

// Round 3
// 140.125 us; speedup vs baseline: 3.1744x; 1.4555x over previous
//
#include <hip/hip_runtime.h>
#include <math.h>

// MultiHeadGAT fused pipeline, round 3.
// k1: MFMA GEMM with T2 both-sides XOR swizzle (pre-swizzled global source,
//     linear LDS dest for global_load_lds, swizzled ds_read) + double-buffered
//     prefetch (T3-minimum 2-phase). Tail: vectorized k3, K-split k4.

#define NH   4
#define TD   768
#define HID  256
#define OD   768
#define BB   16
#define LL   1024
#define RTOT (BB*LL)   // 16384 rows per head

typedef __attribute__((ext_vector_type(8))) short bf16x8;
typedef __attribute__((ext_vector_type(4))) float f32x4;

__device__ __forceinline__ float lrelu(float x) { return fmaxf(x, 0.01f * x); }

__device__ __forceinline__ float waveReduceSum(float v) {
  #pragma unroll
  for (int m = 1; m < 64; m <<= 1) v += __shfl_xor(v, m, 64);
  return v;
}
__device__ __forceinline__ float waveReduceMax(float v) {
  #pragma unroll
  for (int m = 1; m < 64; m <<= 1) v = fmaxf(v, __shfl_xor(v, m, 64));
  return v;
}
__device__ __forceinline__ float red16(float v) {   // reduce across 16-lane group
  v += __shfl_xor(v, 1, 64); v += __shfl_xor(v, 2, 64);
  v += __shfl_xor(v, 4, 64); v += __shfl_xor(v, 8, 64);
  return v;
}

__device__ __forceinline__ unsigned short f2b(float f) {  // f32 -> bf16 RNE
  union { float f; unsigned u; } v; v.f = f;
  unsigned u = v.u;
  return (unsigned short)((u + 0x7fffu + ((u >> 16) & 1u)) >> 16);
}
__device__ __forceinline__ float b2f(unsigned short h) {
  union { unsigned u; float f; } v; v.u = ((unsigned)h) << 16;
  return v.f;
}

__device__ __forceinline__ void gll16(const void* g, void* l) {
  __builtin_amdgcn_global_load_lds(
      (const __attribute__((address_space(1))) unsigned int*)g,
      (__attribute__((address_space(3))) unsigned int*)l, 16, 0, 0);
}

// ---- conversion kernels ----------------------------------------------------
__global__ __launch_bounds__(256) void kconv_t(const float* __restrict__ src,
                                               unsigned short* __restrict__ dst) {
  const size_t i = ((size_t)blockIdx.x * 256 + threadIdx.x) * 8;
  const float4 a = *(const float4*)(src + i);
  const float4 b = *(const float4*)(src + i + 4);
  bf16x8 o;
  o[0] = (short)f2b(a.x); o[1] = (short)f2b(a.y);
  o[2] = (short)f2b(a.z); o[3] = (short)f2b(a.w);
  o[4] = (short)f2b(b.x); o[5] = (short)f2b(b.y);
  o[6] = (short)f2b(b.z); o[7] = (short)f2b(b.w);
  *(bf16x8*)(dst + i) = o;
}

// Wfc fp32 [n][k=768][c=256] -> bf16 transposed Wt [n][c=256][k=768]
__global__ __launch_bounds__(256) void kconv_w(const float* __restrict__ src,
                                               unsigned short* __restrict__ dst) {
  const int ct = blockIdx.x, kt = blockIdx.y, n = blockIdx.z;
  const int t = threadIdx.x;
  __shared__ float tile[64][65];
  #pragma unroll
  for (int i = 0; i < 16; ++i) {
    const int kl = i * 4 + (t >> 6), cl = t & 63;
    tile[kl][cl] = src[(size_t)n * TD * HID + (size_t)(kt * 64 + kl) * HID + ct * 64 + cl];
  }
  __syncthreads();
  #pragma unroll
  for (int i = 0; i < 16; ++i) {
    const int cl = i * 4 + (t >> 6), kl = t & 63;
    dst[(size_t)n * HID * TD + (size_t)(ct * 64 + cl) * TD + kt * 64 + kl] =
        f2b(tile[kl][cl]);
  }
}

// ---- K1: MFMA GEMM + fused LN + a1/a2 dots ---------------------------------
// block = 64 rows x 256 cols of head n; 4 waves, wave wq owns cols [64wq,+64)
// LDS: double-buffered {As[64][64] | Bs[256][64]} bf16, 40KB each -> 80KB.
// Swizzle: LDS[r][kb] = G[r][kb ^ ((r&7)<<4)]; read addr gets the same XOR.
__global__ __launch_bounds__(256) void k1_mfma(
    const unsigned short* __restrict__ Tb,   // [16384][768] bf16
    const unsigned short* __restrict__ Wtb,  // [4][256][768] bf16 (W^T)
    const float* __restrict__ bfc, const float* __restrict__ lng,
    const float* __restrict__ lnb, const float* __restrict__ aw,
    unsigned short* __restrict__ hb,         // [4][16384][256] bf16
    float* __restrict__ sR, float* __restrict__ sC)
{
  const int n    = blockIdx.x >> 8;
  const int mb   = blockIdx.x & 255;
  const int t    = threadIdx.x;
  const int lane = t & 63;
  const int wq   = __builtin_amdgcn_readfirstlane(t >> 6);
  const int cl   = lane & 15;
  const int rg   = lane >> 4;
  const int row0 = mb * 64;

  __shared__ __align__(16) char smem[81920];   // 2 x (8KB A + 32KB B)

  f32x4 acc[4][4];
  #pragma unroll
  for (int mi = 0; mi < 4; ++mi)
    #pragma unroll
    for (int ni = 0; ni < 4; ++ni) acc[mi][ni] = (f32x4){0.f, 0.f, 0.f, 0.f};

  const char* Tg = (const char*)Tb;
  const char* Wg = (const char*)(Wtb + (size_t)n * HID * TD);

  // stage tile k0 into buffer buf (linear LDS dest, pre-swizzled global src)
  #define STAGE(buf, k0)                                                      \
    do {                                                                      \
      char* base_ = smem + (buf) * 40960;                                     \
      _Pragma("unroll")                                                       \
      for (int i_ = 0; i_ < 2; ++i_) {                                        \
        const int off_ = i_ * 4096 + t * 16;                                  \
        const int r_ = off_ >> 7, kb_ = off_ & 127;                           \
        const int kbs_ = kb_ ^ ((r_ & 7) << 4);                               \
        gll16(Tg + ((size_t)(row0 + r_) * TD + (k0)) * 2 + kbs_, base_ + off_);\
      }                                                                       \
      _Pragma("unroll")                                                       \
      for (int i_ = 0; i_ < 8; ++i_) {                                        \
        const int off_ = i_ * 4096 + t * 16;                                  \
        const int c_ = off_ >> 7, kb_ = off_ & 127;                           \
        const int kbs_ = kb_ ^ ((c_ & 7) << 4);                               \
        gll16(Wg + ((size_t)c_ * TD + (k0)) * 2 + kbs_, base_ + 8192 + off_); \
      }                                                                       \
    } while (0)

  STAGE(0, 0);
  __syncthreads();                 // drains vmcnt -> buf0 ready
  int cur = 0;
  for (int kt = 0; kt < 12; ++kt) {
    if (kt < 11) STAGE(cur ^ 1, (kt + 1) * 64);   // async prefetch next tile
    const char* As = smem + cur * 40960;
    const char* Bs = As + 8192;
    #pragma unroll
    for (int ks = 0; ks < 64; ks += 32) {
      bf16x8 av[4], bv[4];
      const int kk2 = (ks + rg * 8) * 2;          // byte offset in k
      #pragma unroll
      for (int mi = 0; mi < 4; ++mi) {
        const int row = mi * 16 + cl;
        av[mi] = *(const bf16x8*)(As + row * 128 + (kk2 ^ ((row & 7) << 4)));
      }
      #pragma unroll
      for (int ni = 0; ni < 4; ++ni) {
        const int row = wq * 64 + ni * 16 + cl;
        bv[ni] = *(const bf16x8*)(Bs + row * 128 + (kk2 ^ ((row & 7) << 4)));
      }
      #pragma unroll
      for (int mi = 0; mi < 4; ++mi)
        #pragma unroll
        for (int ni = 0; ni < 4; ++ni)
          acc[mi][ni] = __builtin_amdgcn_mfma_f32_16x16x32_bf16(
              av[mi], bv[ni], acc[mi][ni], 0, 0, 0);
    }
    __syncthreads();               // all reads of cur done + prefetch landed
    cur ^= 1;
  }
  #undef STAGE

  // ---- epilogue: bias, LN stats (cross-wave), h, a1/a2 dots, bf16 store ----
  float* redS  = (float*)smem;              // [64][4]
  float* redS2 = (float*)(smem + 1024);
  float* redP  = (float*)(smem + 2048);
  float* redC  = (float*)(smem + 3072);
  unsigned short* hs = (unsigned short*)(smem + 4096);   // [64][264] padded

  float bfn[4], gvn[4], bvn[4], a1n[4], a2n[4];
  #pragma unroll
  for (int ni = 0; ni < 4; ++ni) {
    const int c = wq * 64 + ni * 16 + cl;
    bfn[ni] = bfc[n * HID + c];
    gvn[ni] = lng[n * HID + c];
    bvn[ni] = lnb[n * HID + c];
    a1n[ni] = aw[n * (2 * HID) + c];
    a2n[ni] = aw[n * (2 * HID) + HID + c];
  }
  #pragma unroll
  for (int mi = 0; mi < 4; ++mi)
    #pragma unroll
    for (int ni = 0; ni < 4; ++ni) acc[mi][ni] += bfn[ni];

  // (last loop iteration ended with __syncthreads -> smem reusable)
  #pragma unroll
  for (int mi = 0; mi < 4; ++mi) {
    #pragma unroll
    for (int r = 0; r < 4; ++r) {
      const float x0 = acc[mi][0][r], x1 = acc[mi][1][r];
      const float x2 = acc[mi][2][r], x3 = acc[mi][3][r];
      const float s  = red16(x0 + x1 + x2 + x3);
      const float s2 = red16(x0*x0 + x1*x1 + x2*x2 + x3*x3);
      if (cl == 0) {
        const int row = mi * 16 + rg * 4 + r;
        redS[row * 4 + wq] = s; redS2[row * 4 + wq] = s2;
      }
    }
  }
  __syncthreads();
  #pragma unroll
  for (int mi = 0; mi < 4; ++mi) {
    #pragma unroll
    for (int r = 0; r < 4; ++r) {
      const int row = mi * 16 + rg * 4 + r;
      const f32x4 sv  = *(const f32x4*)&redS[row * 4];
      const f32x4 s2v = *(const f32x4*)&redS2[row * 4];
      const float st  = sv.x + sv.y + sv.z + sv.w;
      const float s2t = s2v.x + s2v.y + s2v.z + s2v.w;
      const float mu  = st * (1.f / HID);
      const float var = s2t * (1.f / HID) - mu * mu;
      const float rs  = rsqrtf(var + 1e-5f);
      float pr = 0.f, pc = 0.f;
      #pragma unroll
      for (int ni = 0; ni < 4; ++ni) {
        const float hv = (acc[mi][ni][r] - mu) * rs * gvn[ni] + bvn[ni];
        hs[row * 264 + wq * 64 + ni * 16 + cl] = f2b(hv);
        pr += hv * a1n[ni]; pc += hv * a2n[ni];
      }
      pr = red16(pr); pc = red16(pc);
      if (cl == 0) { redP[row * 4 + wq] = pr; redC[row * 4 + wq] = pc; }
    }
  }
  __syncthreads();
  if (t < 64) {
    const f32x4 pv = *(const f32x4*)&redP[t * 4];
    const f32x4 cv = *(const f32x4*)&redC[t * 4];
    sR[n * RTOT + row0 + t] = pv.x + pv.y + pv.z + pv.w;
    sC[n * RTOT + row0 + t] = cv.x + cv.y + cv.z + cv.w;
  }
  unsigned short* hgb = hb + ((size_t)n * RTOT + row0) * HID;
  #pragma unroll
  for (int i = 0; i < 8; ++i) {
    const int e = i * 2048 + t * 8;
    const int row = e >> 8, c = e & 255;
    const bf16x8 v = *(const bf16x8*)&hs[row * 264 + c];
    *(bf16x8*)&hgb[(size_t)row * HID + c] = v;
  }
}

// K2a: q[n,b,i] = m_i + log(sum_j exp(lrelu(c_i + r_j + ab) - m_i))
__global__ __launch_bounds__(256) void k2_logsumexp(
    const float* __restrict__ sR, const float* __restrict__ sC,
    const float* __restrict__ ab, float* __restrict__ q)
{
  const int n  = blockIdx.x >> 6;
  const int b  = (blockIdx.x >> 2) & 15;
  const int ic = blockIdx.x & 3;
  const int t  = threadIdx.x;
  const int base = (n * BB + b) * LL;

  __shared__ float rl[LL];
  __shared__ float red[4];

  const float4 r4 = ((const float4*)(sR + base))[t];
  ((float4*)rl)[t] = r4;
  float tm = fmaxf(fmaxf(r4.x, r4.y), fmaxf(r4.z, r4.w));
  tm = waveReduceMax(tm);
  if ((t & 63) == 0) red[t >> 6] = tm;
  __syncthreads();
  const float rmax = fmaxf(fmaxf(red[0], red[1]), fmaxf(red[2], red[3]));

  const int i = ic * 256 + t;
  const float ci = sC[base + i] + ab[n];
  const float m = lrelu(ci + rmax);
  float z0 = 0.f, z1 = 0.f, z2 = 0.f, z3 = 0.f;
  #pragma unroll 4
  for (int j4 = 0; j4 < LL / 4; ++j4) {
    const float4 rr = ((const float4*)rl)[j4];
    z0 += __expf(lrelu(ci + rr.x) - m);
    z1 += __expf(lrelu(ci + rr.y) - m);
    z2 += __expf(lrelu(ci + rr.z) - m);
    z3 += __expf(lrelu(ci + rr.w) - m);
  }
  q[base + i] = m + __logf((z0 + z1) + (z2 + z3));
}

// K2b: wcol[n,b,j] = (1/L) * sum_i exp(lrelu(c_i + r_j + ab) - q_i)
__global__ __launch_bounds__(256) void k2_colsum(
    const float* __restrict__ sR, const float* __restrict__ sC,
    const float* __restrict__ ab, const float* __restrict__ q,
    float* __restrict__ wcol)
{
  const int n  = blockIdx.x >> 6;
  const int b  = (blockIdx.x >> 2) & 15;
  const int jc = blockIdx.x & 3;
  const int t  = threadIdx.x;
  const int base = (n * BB + b) * LL;

  __shared__ float cl[LL];
  __shared__ float ql[LL];
  ((float4*)cl)[t] = ((const float4*)(sC + base))[t];
  ((float4*)ql)[t] = ((const float4*)(q + base))[t];
  __syncthreads();

  const int j = jc * 256 + t;
  const float rj = sR[base + j] + ab[n];
  float z0 = 0.f, z1 = 0.f, z2 = 0.f, z3 = 0.f;
  #pragma unroll 4
  for (int i4 = 0; i4 < LL / 4; ++i4) {
    const float4 cc = ((const float4*)cl)[i4];
    const float4 qq = ((const float4*)ql)[i4];
    z0 += __expf(lrelu(cc.x + rj) - qq.x);
    z1 += __expf(lrelu(cc.y + rj) - qq.y);
    z2 += __expf(lrelu(cc.z + rj) - qq.z);
    z3 += __expf(lrelu(cc.w + rj) - qq.w);
  }
  wcol[base + j] = ((z0 + z1) + (z2 + z3)) * (1.f / LL);
}

// K3a: partial[n,b,jc,c] = sum_{j in chunk} wcol[j] * h[n,b,j,c]  (vectorized)
__global__ __launch_bounds__(256) void k3_wsum(
    const unsigned short* __restrict__ h, const float* __restrict__ wcol,
    float* __restrict__ partial)
{
  const int n  = blockIdx.x >> 6;
  const int b  = (blockIdx.x >> 2) & 15;
  const int jc = blockIdx.x & 3;
  const int t  = threadIdx.x;
  const int jl = t >> 5;        // 8 j-lanes
  const int cg = t & 31;        // c0 = cg*8
  __shared__ float wl[256];
  __shared__ float red[8][256];
  const int base = (n * BB + b) * LL;
  wl[t] = wcol[base + jc * 256 + t];
  __syncthreads();
  const unsigned short* hp =
      h + ((size_t)n * RTOT + b * LL + jc * 256) * HID + cg * 8;
  float a0=0,a1=0,a2=0,a3=0,a4=0,a5=0,a6=0,a7=0;
  #pragma unroll 4
  for (int j = jl; j < 256; j += 8) {
    const bf16x8 v = *(const bf16x8*)(hp + (size_t)j * HID);
    const float w = wl[j];
    a0 = fmaf(w, b2f((unsigned short)v[0]), a0);
    a1 = fmaf(w, b2f((unsigned short)v[1]), a1);
    a2 = fmaf(w, b2f((unsigned short)v[2]), a2);
    a3 = fmaf(w, b2f((unsigned short)v[3]), a3);
    a4 = fmaf(w, b2f((unsigned short)v[4]), a4);
    a5 = fmaf(w, b2f((unsigned short)v[5]), a5);
    a6 = fmaf(w, b2f((unsigned short)v[6]), a6);
    a7 = fmaf(w, b2f((unsigned short)v[7]), a7);
  }
  red[jl][cg*8+0]=a0; red[jl][cg*8+1]=a1; red[jl][cg*8+2]=a2; red[jl][cg*8+3]=a3;
  red[jl][cg*8+4]=a4; red[jl][cg*8+5]=a5; red[jl][cg*8+6]=a6; red[jl][cg*8+7]=a7;
  __syncthreads();
  float s = 0.f;
  #pragma unroll
  for (int r = 0; r < 8; ++r) s += red[r][t];
  partial[((n * BB + b) * 4 + jc) * 256 + t] = s;
}

// K3b: sent_raw[b, n*HID + c] = sum_jc partial
__global__ __launch_bounds__(256) void k3_reduce(
    const float* __restrict__ partial, float* __restrict__ sent_raw)
{
  const int n = blockIdx.x >> 4;
  const int b = blockIdx.x & 15;
  const int t = threadIdx.x;
  const int pb = (n * BB + b) * 4 * 256;
  const float v = partial[pb + t] + partial[pb + 256 + t] +
                  partial[pb + 512 + t] + partial[pb + 768 + t];
  sent_raw[b * (NH * HID) + n * HID + t] = v;
}

// K4a: K-split partial GEMM: pcat[kc][b][o] = sum_{k in chunk} sr[b,k]*Wcat[k,o]
// grid = kc(16) x oc(3); each Wcat element read exactly once.
__global__ __launch_bounds__(256) void k4_cat(
    const float* __restrict__ sent_raw, const float* __restrict__ Wcat,
    float* __restrict__ pcat)
{
  const int kc = blockIdx.x / 3;
  const int oc = blockIdx.x % 3;
  const int t  = threadIdx.x;
  __shared__ float s[64][16];    // [kk][b]
  {
    const int kk = t >> 2, b4 = (t & 3) * 4;
    #pragma unroll
    for (int bi = 0; bi < 4; ++bi)
      s[kk][b4 + bi] = sent_raw[(b4 + bi) * (NH * HID) + kc * 64 + kk];
  }
  __syncthreads();
  const int o = oc * 256 + t;
  const float* W = Wcat + (size_t)(kc * 64) * OD + o;
  float acc[BB];
  #pragma unroll
  for (int b = 0; b < BB; ++b) acc[b] = 0.f;
  #pragma unroll 4
  for (int kk = 0; kk < 64; ++kk) {
    const float w = W[(size_t)kk * OD];
    const f32x4 s0 = *(const f32x4*)&s[kk][0];
    const f32x4 s1 = *(const f32x4*)&s[kk][4];
    const f32x4 s2 = *(const f32x4*)&s[kk][8];
    const f32x4 s3 = *(const f32x4*)&s[kk][12];
    acc[0]=fmaf(s0.x,w,acc[0]);  acc[1]=fmaf(s0.y,w,acc[1]);
    acc[2]=fmaf(s0.z,w,acc[2]);  acc[3]=fmaf(s0.w,w,acc[3]);
    acc[4]=fmaf(s1.x,w,acc[4]);  acc[5]=fmaf(s1.y,w,acc[5]);
    acc[6]=fmaf(s1.z,w,acc[6]);  acc[7]=fmaf(s1.w,w,acc[7]);
    acc[8]=fmaf(s2.x,w,acc[8]);  acc[9]=fmaf(s2.y,w,acc[9]);
    acc[10]=fmaf(s2.z,w,acc[10]); acc[11]=fmaf(s2.w,w,acc[11]);
    acc[12]=fmaf(s3.x,w,acc[12]); acc[13]=fmaf(s3.y,w,acc[13]);
    acc[14]=fmaf(s3.z,w,acc[14]); acc[15]=fmaf(s3.w,w,acc[15]);
  }
  float* P = pcat + (size_t)(kc * BB) * OD + o;
  #pragma unroll
  for (int b = 0; b < BB; ++b) P[(size_t)b * OD] = acc[b];
}

// K4b: sent = LN(bcat + sum_kc pcat)
__global__ __launch_bounds__(256) void k4_ln(
    const float* __restrict__ pcat, const float* __restrict__ bcat,
    const float* __restrict__ g, const float* __restrict__ be,
    float* __restrict__ sent, float* __restrict__ out_sent)
{
  const int b = blockIdx.x;
  const int t = threadIdx.x;
  __shared__ float red[4][2];
  float x[3];
  #pragma unroll
  for (int i = 0; i < 3; ++i) {
    const int o = i * 256 + t;
    float v = bcat[o];
    #pragma unroll
    for (int kc = 0; kc < 16; ++kc) v += pcat[(size_t)(kc * BB + b) * OD + o];
    x[i] = v;
  }
  float s  = x[0] + x[1] + x[2];
  float s2 = x[0]*x[0] + x[1]*x[1] + x[2]*x[2];
  s = waveReduceSum(s); s2 = waveReduceSum(s2);
  if ((t & 63) == 0) { red[t >> 6][0] = s; red[t >> 6][1] = s2; }
  __syncthreads();
  s  = red[0][0] + red[1][0] + red[2][0] + red[3][0];
  s2 = red[0][1] + red[1][1] + red[2][1] + red[3][1];
  const float mu  = s * (1.f / OD);
  const float var = s2 * (1.f / OD) - mu * mu;
  const float rs  = rsqrtf(var + 1e-5f);
  #pragma unroll
  for (int i = 0; i < 3; ++i) {
    const int o = i * 256 + t;
    const float y = (x[i] - mu) * rs * g[o] + be[o];
    sent[b * OD + o]     = y;
    out_sent[b * OD + o] = y;
  }
}

// K4c: K-split partials for the three output FCs.
// grid = kc(12) x (i(3) x oc(3)); each W_fcs element read exactly once.
__global__ __launch_bounds__(256) void k4_fcs(
    const float* __restrict__ sent, const float* __restrict__ Wfcs,
    float* __restrict__ pfcs)
{
  const int kc = blockIdx.x / 9;
  const int r  = blockIdx.x % 9;
  const int i  = r / 3, oc = r % 3;
  const int t  = threadIdx.x;
  __shared__ float s[64][16];    // [kk][b]
  {
    const int kk = t >> 2, b4 = (t & 3) * 4;
    #pragma unroll
    for (int bi = 0; bi < 4; ++bi)
      s[kk][b4 + bi] = sent[(b4 + bi) * OD + kc * 64 + kk];
  }
  __syncthreads();
  const int o = oc * 256 + t;
  const float* W = Wfcs + (size_t)i * OD * OD + (size_t)(kc * 64) * OD + o;
  float acc[BB];
  #pragma unroll
  for (int b = 0; b < BB; ++b) acc[b] = 0.f;
  #pragma unroll 4
  for (int kk = 0; kk < 64; ++kk) {
    const float w = W[(size_t)kk * OD];
    const f32x4 s0 = *(const f32x4*)&s[kk][0];
    const f32x4 s1 = *(const f32x4*)&s[kk][4];
    const f32x4 s2 = *(const f32x4*)&s[kk][8];
    const f32x4 s3 = *(const f32x4*)&s[kk][12];
    acc[0]=fmaf(s0.x,w,acc[0]);  acc[1]=fmaf(s0.y,w,acc[1]);
    acc[2]=fmaf(s0.z,w,acc[2]);  acc[3]=fmaf(s0.w,w,acc[3]);
    acc[4]=fmaf(s1.x,w,acc[4]);  acc[5]=fmaf(s1.y,w,acc[5]);
    acc[6]=fmaf(s1.z,w,acc[6]);  acc[7]=fmaf(s1.w,w,acc[7]);
    acc[8]=fmaf(s2.x,w,acc[8]);  acc[9]=fmaf(s2.y,w,acc[9]);
    acc[10]=fmaf(s2.z,w,acc[10]); acc[11]=fmaf(s2.w,w,acc[11]);
    acc[12]=fmaf(s3.x,w,acc[12]); acc[13]=fmaf(s3.y,w,acc[13]);
    acc[14]=fmaf(s3.z,w,acc[14]); acc[15]=fmaf(s3.w,w,acc[15]);
  }
  float* P = pfcs + (size_t)((kc * 3 + i) * BB) * OD + o;
  #pragma unroll
  for (int b = 0; b < BB; ++b) P[(size_t)b * OD] = acc[b];
}

// K4d: out[i][b][o] = bfcs[i,o] + sum_kc pfcs
__global__ __launch_bounds__(256) void k4_red(
    const float* __restrict__ pfcs, const float* __restrict__ bfcs,
    float* __restrict__ out)
{
  const int i = blockIdx.x >> 4;
  const int b = blockIdx.x & 15;
  const int t = threadIdx.x;
  #pragma unroll
  for (int oc = 0; oc < 3; ++oc) {
    const int o = oc * 256 + t;
    float v = bfcs[i * OD + o];
    #pragma unroll
    for (int kc = 0; kc < 12; ++kc)
      v += pfcs[(size_t)((kc * 3 + i) * BB + b) * OD + o];
    out[i * (BB * OD) + b * OD + o] = v;
  }
}

extern "C" void kernel_launch(void* const* d_in, const int* in_sizes, int n_in,
                              void* d_out, int out_size, void* d_ws, size_t ws_size,
                              hipStream_t stream)
{
  const float* T    = (const float*)d_in[0];
  const float* Wfc  = (const float*)d_in[1];
  const float* bfc  = (const float*)d_in[2];
  const float* lng  = (const float*)d_in[3];
  const float* lnb  = (const float*)d_in[4];
  const float* aw   = (const float*)d_in[5];
  const float* ab   = (const float*)d_in[6];
  const float* Wcat = (const float*)d_in[7];
  const float* bcat = (const float*)d_in[8];
  const float* lnOg = (const float*)d_in[9];
  const float* lnOb = (const float*)d_in[10];
  const float* Wfcs = (const float*)d_in[11];
  const float* bfcs = (const float*)d_in[12];
  float* out = (float*)d_out;

  char* W = (char*)d_ws;
  unsigned short* Tb  = (unsigned short*)W;                 // 25,165,824 B
  unsigned short* Wtb = (unsigned short*)(W + 25165824);    //  1,572,864 B
  unsigned short* hb  = (unsigned short*)(W + 26738688);    // 33,554,432 B
  float* sR       = (float*)(W + 60293120);
  float* sC       = sR + NH * RTOT;
  float* q        = sC + NH * RTOT;
  float* wcol     = q + NH * RTOT;
  float* partial  = wcol + NH * RTOT;
  float* sent_raw = partial + NH * BB * 4 * 256;
  float* sent     = sent_raw + BB * NH * HID;
  float* pcat     = sent + BB * OD;                 // 16*16*768
  float* pfcs     = pcat + 16 * BB * OD;            // 36*16*768

  kconv_t     <<<dim3(6144),     dim3(256), 0, stream>>>(T, Tb);
  kconv_w     <<<dim3(4, 12, 4), dim3(256), 0, stream>>>(Wfc, Wtb);
  k1_mfma     <<<dim3(NH * 256), dim3(256), 0, stream>>>(Tb, Wtb, bfc, lng, lnb, aw, hb, sR, sC);
  k2_logsumexp<<<dim3(256),      dim3(256), 0, stream>>>(sR, sC, ab, q);
  k2_colsum   <<<dim3(256),      dim3(256), 0, stream>>>(sR, sC, ab, q, wcol);
  k3_wsum     <<<dim3(256),      dim3(256), 0, stream>>>(hb, wcol, partial);
  k3_reduce   <<<dim3(64),       dim3(256), 0, stream>>>(partial, sent_raw);
  k4_cat      <<<dim3(48),       dim3(256), 0, stream>>>(sent_raw, Wcat, pcat);
  k4_ln       <<<dim3(16),       dim3(256), 0, stream>>>(pcat, bcat, lnOg, lnOb, sent, out + 3 * BB * OD);
  k4_fcs      <<<dim3(108),      dim3(256), 0, stream>>>(sent, Wfcs, pfcs);
  k4_red      <<<dim3(48),       dim3(256), 0, stream>>>(pfcs, bfcs, out);
}

// Round 4
// 109.752 us; speedup vs baseline: 4.0529x; 1.2767x over previous
//
#include <hip/hip_runtime.h>
#include <math.h>

// MultiHeadGAT fused pipeline, round 4.
// k1: 256x256 MFMA tile (8 waves), dbuf 2-phase, source-side XOR swizzle.
// Tail: kconv fused, k2b+k3a fused (wcol stays in LDS), k3_reduce folded
// into k4_cat. 8 kernels total.

#define NH   4
#define TD   768
#define HID  256
#define OD   768
#define BB   16
#define LL   1024
#define RTOT (BB*LL)   // 16384 rows per head

typedef __attribute__((ext_vector_type(8))) short bf16x8;
typedef __attribute__((ext_vector_type(4))) float f32x4;

__device__ __forceinline__ float lrelu(float x) { return fmaxf(x, 0.01f * x); }

__device__ __forceinline__ float waveReduceSum(float v) {
  #pragma unroll
  for (int m = 1; m < 64; m <<= 1) v += __shfl_xor(v, m, 64);
  return v;
}
__device__ __forceinline__ float waveReduceMax(float v) {
  #pragma unroll
  for (int m = 1; m < 64; m <<= 1) v = fmaxf(v, __shfl_xor(v, m, 64));
  return v;
}
__device__ __forceinline__ float red16(float v) {   // reduce across 16-lane group
  v += __shfl_xor(v, 1, 64); v += __shfl_xor(v, 2, 64);
  v += __shfl_xor(v, 4, 64); v += __shfl_xor(v, 8, 64);
  return v;
}

__device__ __forceinline__ unsigned short f2b(float f) {  // f32 -> bf16 RNE
  union { float f; unsigned u; } v; v.f = f;
  unsigned u = v.u;
  return (unsigned short)((u + 0x7fffu + ((u >> 16) & 1u)) >> 16);
}
__device__ __forceinline__ float b2f(unsigned short h) {
  union { unsigned u; float f; } v; v.u = ((unsigned)h) << 16;
  return v.f;
}

__device__ __forceinline__ void gll16(const void* g, void* l) {
  __builtin_amdgcn_global_load_lds(
      (const __attribute__((address_space(1))) unsigned int*)g,
      (__attribute__((address_space(3))) unsigned int*)l, 16, 0, 0);
}

// ---- fused conversion kernel ----------------------------------------------
// blocks [0,6144): T fp32 -> bf16.  blocks [6144,6336): Wfc -> Wt bf16 (transposed)
__global__ __launch_bounds__(256) void kconv(const float* __restrict__ T,
                                             const float* __restrict__ Wfc,
                                             unsigned short* __restrict__ Tb,
                                             unsigned short* __restrict__ Wtb) {
  __shared__ float tile[64][65];
  const int t = threadIdx.x;
  if (blockIdx.x < 6144) {
    const size_t i = ((size_t)blockIdx.x * 256 + t) * 8;
    const float4 a = *(const float4*)(T + i);
    const float4 b = *(const float4*)(T + i + 4);
    bf16x8 o;
    o[0] = (short)f2b(a.x); o[1] = (short)f2b(a.y);
    o[2] = (short)f2b(a.z); o[3] = (short)f2b(a.w);
    o[4] = (short)f2b(b.x); o[5] = (short)f2b(b.y);
    o[6] = (short)f2b(b.z); o[7] = (short)f2b(b.w);
    *(bf16x8*)(Tb + i) = o;
  } else {
    const int b2 = blockIdx.x - 6144;       // [0,192)
    const int ct = b2 & 3;
    const int kt = (b2 >> 2) % 12;
    const int n  = b2 / 48;
    #pragma unroll
    for (int i = 0; i < 16; ++i) {
      const int kl = i * 4 + (t >> 6), cl = t & 63;
      tile[kl][cl] =
          Wfc[(size_t)n * TD * HID + (size_t)(kt * 64 + kl) * HID + ct * 64 + cl];
    }
    __syncthreads();
    #pragma unroll
    for (int i = 0; i < 16; ++i) {
      const int cl = i * 4 + (t >> 6), kl = t & 63;
      Wtb[(size_t)n * HID * TD + (size_t)(ct * 64 + cl) * TD + kt * 64 + kl] =
          f2b(tile[kl][cl]);
    }
  }
}

// ---- K1: 256x256 MFMA GEMM + fused LN + a1/a2 dots -------------------------
// grid = 4 heads x 64 m-blocks; 8 waves (2n x 4m), wave tile 64 rows x 128 cols.
// LDS: dbuf x (As[256][64] | Bs[256][64]) bf16 = 2 x 64KB = 128KB.
// Swizzle: LDS[r][kb] = G[r][kb ^ ((r&7)<<4)]; ds_read addr gets same XOR.
__global__ __launch_bounds__(512) void k1_mfma(
    const unsigned short* __restrict__ Tb,   // [16384][768] bf16
    const unsigned short* __restrict__ Wtb,  // [4][256][768] bf16 (W^T)
    const float* __restrict__ bfc, const float* __restrict__ lng,
    const float* __restrict__ lnb, const float* __restrict__ aw,
    unsigned short* __restrict__ hb,         // [4][16384][256] bf16
    float* __restrict__ sR, float* __restrict__ sC)
{
  const int n    = blockIdx.x >> 6;
  const int mb   = blockIdx.x & 63;
  const int t    = threadIdx.x;
  const int lane = t & 63;
  const int wq   = __builtin_amdgcn_readfirstlane(t >> 6);
  const int wm   = wq >> 1;          // 0..3  (m quarter)
  const int wn   = wq & 1;           // 0..1  (n half)
  const int cl   = lane & 15;
  const int rg   = lane >> 4;
  const int row0 = mb * 256;

  __shared__ __align__(16) char smem[131072];

  f32x4 acc[4][8];
  #pragma unroll
  for (int mi = 0; mi < 4; ++mi)
    #pragma unroll
    for (int ni = 0; ni < 8; ++ni) acc[mi][ni] = (f32x4){0.f, 0.f, 0.f, 0.f};

  const char* Tg = (const char*)Tb;
  const char* Wg = (const char*)(Wtb + (size_t)n * HID * TD);

  #define STAGE(buf, k0)                                                       \
    do {                                                                       \
      char* base_ = smem + (buf) * 65536;                                      \
      _Pragma("unroll")                                                        \
      for (int i_ = 0; i_ < 4; ++i_) {                                         \
        const int off_ = i_ * 8192 + t * 16;                                   \
        const int r_ = off_ >> 7, kb_ = off_ & 127;                            \
        const int kbs_ = kb_ ^ ((r_ & 7) << 4);                                \
        gll16(Tg + ((size_t)(row0 + r_) * TD + (k0)) * 2 + kbs_, base_ + off_);\
      }                                                                        \
      _Pragma("unroll")                                                        \
      for (int i_ = 0; i_ < 4; ++i_) {                                         \
        const int off_ = i_ * 8192 + t * 16;                                   \
        const int c_ = off_ >> 7, kb_ = off_ & 127;                            \
        const int kbs_ = kb_ ^ ((c_ & 7) << 4);                                \
        gll16(Wg + ((size_t)c_ * TD + (k0)) * 2 + kbs_, base_ + 32768 + off_); \
      }                                                                        \
    } while (0)

  STAGE(0, 0);
  __syncthreads();                 // drains vmcnt -> buf0 ready
  int cur = 0;
  for (int kt = 0; kt < 12; ++kt) {
    if (kt < 11) STAGE(cur ^ 1, (kt + 1) * 64);   // issue next-tile prefetch
    const char* As = smem + cur * 65536;
    const char* Bs = As + 32768;
    #pragma unroll
    for (int ks = 0; ks < 64; ks += 32) {
      bf16x8 av[4], bv[8];
      const int kk2 = (ks + rg * 8) * 2;
      #pragma unroll
      for (int mi = 0; mi < 4; ++mi) {
        const int row = wm * 64 + mi * 16 + cl;
        av[mi] = *(const bf16x8*)(As + row * 128 + (kk2 ^ ((row & 7) << 4)));
      }
      #pragma unroll
      for (int ni = 0; ni < 8; ++ni) {
        const int row = wn * 128 + ni * 16 + cl;
        bv[ni] = *(const bf16x8*)(Bs + row * 128 + (kk2 ^ ((row & 7) << 4)));
      }
      #pragma unroll
      for (int mi = 0; mi < 4; ++mi)
        #pragma unroll
        for (int ni = 0; ni < 8; ++ni)
          acc[mi][ni] = __builtin_amdgcn_mfma_f32_16x16x32_bf16(
              av[mi], bv[ni], acc[mi][ni], 0, 0, 0);
    }
    __syncthreads();               // reads of cur done + prefetch landed
    cur ^= 1;
  }
  #undef STAGE

  // ---- epilogue ----
  unsigned short* hs = (unsigned short*)smem;        // [64][264] per chunk
  float* redS  = (float*)(smem + 36864);             // [256][2]
  float* redS2 = (float*)(smem + 38912);
  float* redP  = (float*)(smem + 40960);
  float* redC  = (float*)(smem + 43008);

  float bfn[8], gvn[8], bvn[8], a1n[8], a2n[8];
  #pragma unroll
  for (int ni = 0; ni < 8; ++ni) {
    const int c = wn * 128 + ni * 16 + cl;
    bfn[ni] = bfc[n * HID + c];
    gvn[ni] = lng[n * HID + c];
    bvn[ni] = lnb[n * HID + c];
    a1n[ni] = aw[n * (2 * HID) + c];
    a2n[ni] = aw[n * (2 * HID) + HID + c];
  }

  // E1: per-row sum / sumsq (this wave covers half the row -> LDS combine)
  #pragma unroll
  for (int mi = 0; mi < 4; ++mi) {
    #pragma unroll
    for (int r = 0; r < 4; ++r) {
      float s = 0.f, s2 = 0.f;
      #pragma unroll
      for (int ni = 0; ni < 8; ++ni) {
        const float x = acc[mi][ni][r] + bfn[ni];
        acc[mi][ni][r] = x;
        s += x; s2 += x * x;
      }
      s = red16(s); s2 = red16(s2);
      if (cl == 0) {
        const int row = wm * 64 + mi * 16 + rg * 4 + r;
        redS [row * 2 + wn] = s;
        redS2[row * 2 + wn] = s2;
      }
    }
  }
  __syncthreads();

  // E2: normalize, a1/a2 dots
  #pragma unroll
  for (int mi = 0; mi < 4; ++mi) {
    #pragma unroll
    for (int r = 0; r < 4; ++r) {
      const int row = wm * 64 + mi * 16 + rg * 4 + r;
      const float st  = redS [row * 2] + redS [row * 2 + 1];
      const float s2t = redS2[row * 2] + redS2[row * 2 + 1];
      const float mu  = st * (1.f / HID);
      const float var = s2t * (1.f / HID) - mu * mu;
      const float rs  = rsqrtf(var + 1e-5f);
      float pr = 0.f, pc = 0.f;
      #pragma unroll
      for (int ni = 0; ni < 8; ++ni) {
        const float hv = (acc[mi][ni][r] - mu) * rs * gvn[ni] + bvn[ni];
        acc[mi][ni][r] = hv;
        pr += hv * a1n[ni]; pc += hv * a2n[ni];
      }
      pr = red16(pr); pc = red16(pc);
      if (cl == 0) { redP[row * 2 + wn] = pr; redC[row * 2 + wn] = pc; }
    }
  }
  __syncthreads();
  if (t < 256) {
    sR[n * RTOT + row0 + t] = redP[t * 2] + redP[t * 2 + 1];
    sC[n * RTOT + row0 + t] = redC[t * 2] + redC[t * 2 + 1];
  }

  // E3: h store via LDS bounce, 4 chunks (chunk c = fragment-row group mi=c)
  unsigned short* hgb = hb + ((size_t)n * RTOT + row0) * HID;
  #pragma unroll
  for (int c = 0; c < 4; ++c) {
    #pragma unroll
    for (int ni = 0; ni < 8; ++ni)
      #pragma unroll
      for (int r = 0; r < 4; ++r) {
        const int lr  = wm * 16 + rg * 4 + r;
        const int col = wn * 128 + ni * 16 + cl;
        hs[lr * 264 + col] = f2b(acc[c][ni][r]);
      }
    __syncthreads();
    #pragma unroll
    for (int i = 0; i < 4; ++i) {
      const int idx = i * 4096 + t * 8;
      const int lr = idx >> 8, cc = idx & 255;
      const int grow = (lr >> 4) * 64 + c * 16 + (lr & 15);
      *(bf16x8*)&hgb[(size_t)grow * HID + cc] = *(const bf16x8*)&hs[lr * 264 + cc];
    }
    __syncthreads();
  }
}

// K2a: q[n,b,i] = m_i + log(sum_j exp(lrelu(c_i + r_j + ab) - m_i))
// 512 blocks: i-chunks of 128, two threads per i (j split in halves).
__global__ __launch_bounds__(256) void k2_lse(
    const float* __restrict__ sR, const float* __restrict__ sC,
    const float* __restrict__ ab, float* __restrict__ q)
{
  const int n  = blockIdx.x >> 7;
  const int b  = (blockIdx.x >> 3) & 15;
  const int ic = blockIdx.x & 7;
  const int t  = threadIdx.x;
  const int base = (n * BB + b) * LL;

  __shared__ float rl[LL];
  __shared__ float red[4];

  const float4 r4 = ((const float4*)(sR + base))[t];
  ((float4*)rl)[t] = r4;
  float tm = fmaxf(fmaxf(r4.x, r4.y), fmaxf(r4.z, r4.w));
  tm = waveReduceMax(tm);
  if ((t & 63) == 0) red[t >> 6] = tm;
  __syncthreads();
  const float rmax = fmaxf(fmaxf(red[0], red[1]), fmaxf(red[2], red[3]));

  const int i  = ic * 128 + (t >> 1);
  const int jh = t & 1;
  const float ci = sC[base + i] + ab[n];
  const float m = lrelu(ci + rmax);
  float z0 = 0.f, z1 = 0.f, z2 = 0.f, z3 = 0.f;
  #pragma unroll 4
  for (int j4 = jh * 128; j4 < jh * 128 + 128; ++j4) {
    const float4 rr = ((const float4*)rl)[j4];
    z0 += __expf(lrelu(ci + rr.x) - m);
    z1 += __expf(lrelu(ci + rr.y) - m);
    z2 += __expf(lrelu(ci + rr.z) - m);
    z3 += __expf(lrelu(ci + rr.w) - m);
  }
  float z = (z0 + z1) + (z2 + z3);
  z += __shfl_xor(z, 1, 64);
  if (!jh) q[base + i] = m + __logf(z);
}

// K23: fused colsum + weighted h-sum. 512 blocks: (n,b) x 8 j-chunks of 128.
// phase1: wcol for the chunk's 128 j (kept in LDS); phase2: partial[c] =
// sum_{j in chunk} wcol[j] * h[n,b,j,c].
__global__ __launch_bounds__(256) void k23_colw(
    const unsigned short* __restrict__ h, const float* __restrict__ sR,
    const float* __restrict__ sC, const float* __restrict__ ab,
    const float* __restrict__ q, float* __restrict__ partial)
{
  const int n  = blockIdx.x >> 7;
  const int b  = (blockIdx.x >> 3) & 15;
  const int jc = blockIdx.x & 7;
  const int t  = threadIdx.x;
  const int base = (n * BB + b) * LL;

  __shared__ float cls[LL];
  __shared__ float qls[LL];
  __shared__ float wl[128];
  __shared__ float red2[8][256];

  ((float4*)cls)[t] = ((const float4*)(sC + base))[t];
  ((float4*)qls)[t] = ((const float4*)(q + base))[t];
  __syncthreads();

  // phase 1: wcol for 128 j's; 2 threads per j (i split in halves)
  {
    const int j  = jc * 128 + (t >> 1);
    const int ih = t & 1;
    const float rj = sR[base + j] + ab[n];
    float z0 = 0.f, z1 = 0.f, z2 = 0.f, z3 = 0.f;
    #pragma unroll 4
    for (int i4 = ih * 128; i4 < ih * 128 + 128; ++i4) {
      const float4 cc = ((const float4*)cls)[i4];
      const float4 qq = ((const float4*)qls)[i4];
      z0 += __expf(lrelu(cc.x + rj) - qq.x);
      z1 += __expf(lrelu(cc.y + rj) - qq.y);
      z2 += __expf(lrelu(cc.z + rj) - qq.z);
      z3 += __expf(lrelu(cc.w + rj) - qq.w);
    }
    float z = (z0 + z1) + (z2 + z3);
    z += __shfl_xor(z, 1, 64);
    if (!ih) wl[t >> 1] = z * (1.f / LL);
  }
  __syncthreads();

  // phase 2: weighted column sum over the 128 j's
  const int jl = t >> 5;        // 8 j-lanes
  const int cg = t & 31;        // c0 = cg*8
  const unsigned short* hp =
      h + ((size_t)n * RTOT + b * LL + jc * 128) * HID + cg * 8;
  float a0=0,a1=0,a2=0,a3=0,a4=0,a5=0,a6=0,a7=0;
  #pragma unroll 4
  for (int j = jl; j < 128; j += 8) {
    const bf16x8 v = *(const bf16x8*)(hp + (size_t)j * HID);
    const float w = wl[j];
    a0 = fmaf(w, b2f((unsigned short)v[0]), a0);
    a1 = fmaf(w, b2f((unsigned short)v[1]), a1);
    a2 = fmaf(w, b2f((unsigned short)v[2]), a2);
    a3 = fmaf(w, b2f((unsigned short)v[3]), a3);
    a4 = fmaf(w, b2f((unsigned short)v[4]), a4);
    a5 = fmaf(w, b2f((unsigned short)v[5]), a5);
    a6 = fmaf(w, b2f((unsigned short)v[6]), a6);
    a7 = fmaf(w, b2f((unsigned short)v[7]), a7);
  }
  red2[jl][cg*8+0]=a0; red2[jl][cg*8+1]=a1; red2[jl][cg*8+2]=a2; red2[jl][cg*8+3]=a3;
  red2[jl][cg*8+4]=a4; red2[jl][cg*8+5]=a5; red2[jl][cg*8+6]=a6; red2[jl][cg*8+7]=a7;
  __syncthreads();
  float s = 0.f;
  #pragma unroll
  for (int r = 0; r < 8; ++r) s += red2[r][t];
  partial[((n * BB + b) * 8 + jc) * 256 + t] = s;
}

// K4a: K-split partial GEMM (k3_reduce folded into the staging):
// pcat[kc][b][o] = sum_{k in chunk} sent_raw[b,k] * Wcat[k,o]
__global__ __launch_bounds__(256) void k4_cat(
    const float* __restrict__ partial, const float* __restrict__ Wcat,
    float* __restrict__ pcat)
{
  const int kc = blockIdx.x / 3;     // [0,16)
  const int oc = blockIdx.x % 3;
  const int t  = threadIdx.x;
  __shared__ float s[64][16];        // [kk][b]
  {
    const int kk = t >> 2, b4 = (t & 3) * 4;
    const int n = kc >> 2;
    const int c = (kc & 3) * 64 + kk;
    #pragma unroll
    for (int bi = 0; bi < 4; ++bi) {
      const int b = b4 + bi;
      const float* pb = partial + (size_t)((n * BB + b) * 8) * 256 + c;
      float v = 0.f;
      #pragma unroll
      for (int j = 0; j < 8; ++j) v += pb[j * 256];
      s[kk][b] = v;
    }
  }
  __syncthreads();
  const int o = oc * 256 + t;
  const float* W = Wcat + (size_t)(kc * 64) * OD + o;
  float acc[BB];
  #pragma unroll
  for (int b = 0; b < BB; ++b) acc[b] = 0.f;
  #pragma unroll 4
  for (int kk = 0; kk < 64; ++kk) {
    const float w = W[(size_t)kk * OD];
    const f32x4 s0 = *(const f32x4*)&s[kk][0];
    const f32x4 s1 = *(const f32x4*)&s[kk][4];
    const f32x4 s2 = *(const f32x4*)&s[kk][8];
    const f32x4 s3 = *(const f32x4*)&s[kk][12];
    acc[0]=fmaf(s0.x,w,acc[0]);  acc[1]=fmaf(s0.y,w,acc[1]);
    acc[2]=fmaf(s0.z,w,acc[2]);  acc[3]=fmaf(s0.w,w,acc[3]);
    acc[4]=fmaf(s1.x,w,acc[4]);  acc[5]=fmaf(s1.y,w,acc[5]);
    acc[6]=fmaf(s1.z,w,acc[6]);  acc[7]=fmaf(s1.w,w,acc[7]);
    acc[8]=fmaf(s2.x,w,acc[8]);  acc[9]=fmaf(s2.y,w,acc[9]);
    acc[10]=fmaf(s2.z,w,acc[10]); acc[11]=fmaf(s2.w,w,acc[11]);
    acc[12]=fmaf(s3.x,w,acc[12]); acc[13]=fmaf(s3.y,w,acc[13]);
    acc[14]=fmaf(s3.z,w,acc[14]); acc[15]=fmaf(s3.w,w,acc[15]);
  }
  float* P = pcat + (size_t)(kc * BB) * OD + o;
  #pragma unroll
  for (int b = 0; b < BB; ++b) P[(size_t)b * OD] = acc[b];
}

// K4b: sent = LN(bcat + sum_kc pcat)
__global__ __launch_bounds__(256) void k4_ln(
    const float* __restrict__ pcat, const float* __restrict__ bcat,
    const float* __restrict__ g, const float* __restrict__ be,
    float* __restrict__ sent, float* __restrict__ out_sent)
{
  const int b = blockIdx.x;
  const int t = threadIdx.x;
  __shared__ float red[4][2];
  float x[3];
  #pragma unroll
  for (int i = 0; i < 3; ++i) {
    const int o = i * 256 + t;
    float v = bcat[o];
    #pragma unroll
    for (int kc = 0; kc < 16; ++kc) v += pcat[(size_t)(kc * BB + b) * OD + o];
    x[i] = v;
  }
  float s  = x[0] + x[1] + x[2];
  float s2 = x[0]*x[0] + x[1]*x[1] + x[2]*x[2];
  s = waveReduceSum(s); s2 = waveReduceSum(s2);
  if ((t & 63) == 0) { red[t >> 6][0] = s; red[t >> 6][1] = s2; }
  __syncthreads();
  s  = red[0][0] + red[1][0] + red[2][0] + red[3][0];
  s2 = red[0][1] + red[1][1] + red[2][1] + red[3][1];
  const float mu  = s * (1.f / OD);
  const float var = s2 * (1.f / OD) - mu * mu;
  const float rs  = rsqrtf(var + 1e-5f);
  #pragma unroll
  for (int i = 0; i < 3; ++i) {
    const int o = i * 256 + t;
    const float y = (x[i] - mu) * rs * g[o] + be[o];
    sent[b * OD + o]     = y;
    out_sent[b * OD + o] = y;
  }
}

// K4c: K-split partials for the three output FCs.
__global__ __launch_bounds__(256) void k4_fcs(
    const float* __restrict__ sent, const float* __restrict__ Wfcs,
    float* __restrict__ pfcs)
{
  const int kc = blockIdx.x / 9;
  const int r  = blockIdx.x % 9;
  const int i  = r / 3, oc = r % 3;
  const int t  = threadIdx.x;
  __shared__ float s[64][16];    // [kk][b]
  {
    const int kk = t >> 2, b4 = (t & 3) * 4;
    #pragma unroll
    for (int bi = 0; bi < 4; ++bi)
      s[kk][b4 + bi] = sent[(b4 + bi) * OD + kc * 64 + kk];
  }
  __syncthreads();
  const int o = oc * 256 + t;
  const float* W = Wfcs + (size_t)i * OD * OD + (size_t)(kc * 64) * OD + o;
  float acc[BB];
  #pragma unroll
  for (int b = 0; b < BB; ++b) acc[b] = 0.f;
  #pragma unroll 4
  for (int kk = 0; kk < 64; ++kk) {
    const float w = W[(size_t)kk * OD];
    const f32x4 s0 = *(const f32x4*)&s[kk][0];
    const f32x4 s1 = *(const f32x4*)&s[kk][4];
    const f32x4 s2 = *(const f32x4*)&s[kk][8];
    const f32x4 s3 = *(const f32x4*)&s[kk][12];
    acc[0]=fmaf(s0.x,w,acc[0]);  acc[1]=fmaf(s0.y,w,acc[1]);
    acc[2]=fmaf(s0.z,w,acc[2]);  acc[3]=fmaf(s0.w,w,acc[3]);
    acc[4]=fmaf(s1.x,w,acc[4]);  acc[5]=fmaf(s1.y,w,acc[5]);
    acc[6]=fmaf(s1.z,w,acc[6]);  acc[7]=fmaf(s1.w,w,acc[7]);
    acc[8]=fmaf(s2.x,w,acc[8]);  acc[9]=fmaf(s2.y,w,acc[9]);
    acc[10]=fmaf(s2.z,w,acc[10]); acc[11]=fmaf(s2.w,w,acc[11]);
    acc[12]=fmaf(s3.x,w,acc[12]); acc[13]=fmaf(s3.y,w,acc[13]);
    acc[14]=fmaf(s3.z,w,acc[14]); acc[15]=fmaf(s3.w,w,acc[15]);
  }
  float* P = pfcs + (size_t)((kc * 3 + i) * BB) * OD + o;
  #pragma unroll
  for (int b = 0; b < BB; ++b) P[(size_t)b * OD] = acc[b];
}

// K4d: out[i][b][o] = bfcs[i,o] + sum_kc pfcs
__global__ __launch_bounds__(256) void k4_red(
    const float* __restrict__ pfcs, const float* __restrict__ bfcs,
    float* __restrict__ out)
{
  const int i = blockIdx.x >> 4;
  const int b = blockIdx.x & 15;
  const int t = threadIdx.x;
  #pragma unroll
  for (int oc = 0; oc < 3; ++oc) {
    const int o = oc * 256 + t;
    float v = bfcs[i * OD + o];
    #pragma unroll
    for (int kc = 0; kc < 12; ++kc)
      v += pfcs[(size_t)((kc * 3 + i) * BB + b) * OD + o];
    out[i * (BB * OD) + b * OD + o] = v;
  }
}

extern "C" void kernel_launch(void* const* d_in, const int* in_sizes, int n_in,
                              void* d_out, int out_size, void* d_ws, size_t ws_size,
                              hipStream_t stream)
{
  const float* T    = (const float*)d_in[0];
  const float* Wfc  = (const float*)d_in[1];
  const float* bfc  = (const float*)d_in[2];
  const float* lng  = (const float*)d_in[3];
  const float* lnb  = (const float*)d_in[4];
  const float* aw   = (const float*)d_in[5];
  const float* ab   = (const float*)d_in[6];
  const float* Wcat = (const float*)d_in[7];
  const float* bcat = (const float*)d_in[8];
  const float* lnOg = (const float*)d_in[9];
  const float* lnOb = (const float*)d_in[10];
  const float* Wfcs = (const float*)d_in[11];
  const float* bfcs = (const float*)d_in[12];
  float* out = (float*)d_out;

  char* W = (char*)d_ws;
  unsigned short* Tb  = (unsigned short*)W;                 // 25,165,824 B
  unsigned short* Wtb = (unsigned short*)(W + 25165824);    //  1,572,864 B
  unsigned short* hb  = (unsigned short*)(W + 26738688);    // 33,554,432 B
  float* sR      = (float*)(W + 60293120);                  // 65536 f
  float* sC      = sR + NH * RTOT;                          // 65536 f
  float* q       = sC + NH * RTOT;                          // 65536 f
  float* partial = q + NH * RTOT;                           // 131072 f
  float* sent    = partial + NH * BB * 8 * 256;             // 12288 f
  float* pcat    = sent + BB * OD;                          // 196608 f
  float* pfcs    = pcat + 16 * BB * OD;                     // 442368 f

  kconv   <<<dim3(6336), dim3(256), 0, stream>>>(T, Wfc, Tb, Wtb);
  k1_mfma <<<dim3(256),  dim3(512), 0, stream>>>(Tb, Wtb, bfc, lng, lnb, aw, hb, sR, sC);
  k2_lse  <<<dim3(512),  dim3(256), 0, stream>>>(sR, sC, ab, q);
  k23_colw<<<dim3(512),  dim3(256), 0, stream>>>(hb, sR, sC, ab, q, partial);
  k4_cat  <<<dim3(48),   dim3(256), 0, stream>>>(partial, Wcat, pcat);
  k4_ln   <<<dim3(16),   dim3(256), 0, stream>>>(pcat, bcat, lnOg, lnOb, sent, out + 3 * BB * OD);
  k4_fcs  <<<dim3(108),  dim3(256), 0, stream>>>(sent, Wfcs, pfcs);
  k4_red  <<<dim3(48),   dim3(256), 0, stream>>>(pfcs, bfcs, out);
}